// Round 5
// baseline (663.534 us; speedup 1.0000x reference)
//
#include <hip/hip_runtime.h>
#include <hip/hip_bf16.h>
#include <math.h>

#define N_NODES 50000
#define N_EDGES 800000
#define BN_EPS  1e-5f
#define SCAN_NB 49     // ceil(50000/1024)
#define AGG_NB  2048   // agg grid blocks

// ---- workspace layout (float-element offsets) ----
#define OFS_RELW   0
#define OFS_K      20480
#define OFS_Q      (OFS_K + 5000000)
#define OFS_V      (OFS_Q + 5000000)
#define OFS_ATTP   (OFS_V + 5000000)
#define OFS_BNPART (OFS_ATTP + 800000)          // 200 * AGG_NB
#define OFS_BNSC   (OFS_BNPART + 200 * AGG_NB)
#define OFS_BNSH   (OFS_BNSC + 128)
// int region
#define OFS_CNT    (OFS_BNSH + 128)
#define OFS_PART   (OFS_CNT + 50176)
#define OFS_BSUM   (OFS_PART + 50176)
#define OFS_OFFS   (OFS_BSUM + 64)
#define OFS_CURS   (OFS_OFFS + 50176)
#define OFS_PERM   (OFS_CURS + 50176)
#define OFS_PSRC   (OFS_PERM + 800000)
#define OFS_WT     (OFS_PSRC + 800000)          // 4 * 100 * 100 transposed W
#define WS_ELEMS   (OFS_WT + 40960)

__device__ __forceinline__ const float* rfl_cptr(const float* p) {
    uint64_t v = (uint64_t)p;
    uint32_t lo = __builtin_amdgcn_readfirstlane((uint32_t)v);
    uint32_t hi = __builtin_amdgcn_readfirstlane((uint32_t)(v >> 32));
    return (const float*)(((uint64_t)hi << 32) | lo);
}
__device__ __forceinline__ float* rfl_ptr(float* p) {
    uint64_t v = (uint64_t)p;
    uint32_t lo = __builtin_amdgcn_readfirstlane((uint32_t)v);
    uint32_t hi = __builtin_amdgcn_readfirstlane((uint32_t)(v >> 32));
    return (float*)(((uint64_t)hi << 32) | lo);
}

// rel_w[r][c] = sum_b w_comp[r][b] * relation_att[b][c]
__global__ __launch_bounds__(256) void relw_kernel(
    const float* __restrict__ wcomp, const float* __restrict__ ratt,
    float* __restrict__ relw)
{
    int o = blockIdx.x * 256 + threadIdx.x;
    if (o >= 200 * 100) return;
    int r = o / 100, c = o % 100;
    float acc = 0.f;
    #pragma unroll 10
    for (int b = 0; b < 50; ++b) acc += wcomp[r * 50 + b] * ratt[b * 100 + c];
    relw[o] = acc;
}

// transpose 4 projection matrices: Wt[m][d][c] = Wm[c][d]
__global__ __launch_bounds__(256) void wt_kernel(
    const float* __restrict__ Wk, const float* __restrict__ Wq,
    const float* __restrict__ Wv, const float* __restrict__ Ws,
    float* __restrict__ Wt)
{
    int o = blockIdx.x * 256 + threadIdx.x;
    if (o >= 40000) return;
    int m = o / 10000, rem = o % 10000, d = rem / 100, c = rem % 100;
    const float* W = (m == 0) ? Wk : (m == 1) ? Wq : (m == 2) ? Wv : Ws;
    Wt[o] = W[c * 100 + d];
}

// fused projections: 4 waves/block, wave w owns matrix w, lane owns node.
// W rows (d-major) streamed through scalar loads; full output row in regs,
// stored as one burst (fully-dirtied cache lines -> no write amplification).
__global__ __launch_bounds__(256) void proj_kernel(
    const float* __restrict__ X, const float* __restrict__ Wt,
    const float* __restrict__ bk, const float* __restrict__ bq,
    const float* __restrict__ bv, const float* __restrict__ bs,
    float* __restrict__ ko, float* __restrict__ qo,
    float* __restrict__ vo, float* __restrict__ so)
{
    __shared__ float Xs[64][101];   // pad 101: column reads conflict-free
    const int tid = threadIdx.x;
    const int nb = blockIdx.x * 64;

    for (int idx = tid; idx < 6400; idx += 256) {
        int n = idx / 100, d = idx % 100;
        int node = nb + n;
        Xs[n][d] = (node < N_NODES) ? X[(size_t)node * 100 + d] : 0.f;
    }
    __syncthreads();

    const int wid  = tid >> 6;
    const int lane = tid & 63;
    const float* bm[4] = {bk, bq, bv, bs};
    float*       om[4] = {ko, qo, vo, so};
    const float* Wp = rfl_cptr(Wt + wid * 10000);
    const float* bp = rfl_cptr(bm[wid]);
    float*       op = rfl_ptr(om[wid]);

    const int node = nb + lane;

    float4 acc[25];
    #pragma unroll
    for (int i = 0; i < 25; ++i) acc[i] = make_float4(0.f, 0.f, 0.f, 0.f);

    for (int d = 0; d < 100; ++d) {
        const float x = Xs[lane][d];
        const float4* wr = (const float4*)(Wp + d * 100);   // uniform -> s_load
        #pragma unroll
        for (int c4 = 0; c4 < 25; ++c4) {
            const float4 w = wr[c4];
            acc[c4].x += x * w.x;
            acc[c4].y += x * w.y;
            acc[c4].z += x * w.z;
            acc[c4].w += x * w.w;
        }
    }

    if (node < N_NODES) {
        float4* orow = (float4*)(op + (size_t)node * 100);
        const float4* b4 = (const float4*)bp;
        #pragma unroll
        for (int c4 = 0; c4 < 25; ++c4) {
            const float4 bb = b4[c4];
            float4 r = acc[c4];
            r.x += bb.x; r.y += bb.y; r.z += bb.z; r.w += bb.w;
            orow[c4] = r;
        }
    }
}

__global__ __launch_bounds__(256) void hist_kernel(
    const int* __restrict__ dst, int* __restrict__ cnt)
{
    int e = blockIdx.x * 256 + threadIdx.x;
    if (e < N_EDGES) atomicAdd(&cnt[dst[e]], 1);
}

__global__ __launch_bounds__(1024) void scanA_kernel(
    const int* __restrict__ cnt, int* __restrict__ partial, int* __restrict__ bsum)
{
    __shared__ int buf[1024];
    int tid = threadIdx.x;
    int i = blockIdx.x * 1024 + tid;
    int val = (i < N_NODES) ? cnt[i] : 0;
    buf[tid] = val;
    __syncthreads();
    for (int off = 1; off < 1024; off <<= 1) {
        int t = (tid >= off) ? buf[tid - off] : 0;
        __syncthreads();
        buf[tid] += t;
        __syncthreads();
    }
    int incl = buf[tid];
    if (i < N_NODES) partial[i] = incl - val;
    if (tid == 1023) bsum[blockIdx.x] = incl;
}

__global__ __launch_bounds__(1024) void scanB_kernel(
    const int* __restrict__ partial, const int* __restrict__ bsum,
    int* __restrict__ offs)
{
    __shared__ int bs[64];
    int tid = threadIdx.x;
    if (tid < SCAN_NB) bs[tid] = bsum[tid];
    __syncthreads();
    if (tid == 0) {
        int run = 0;
        for (int b = 0; b < SCAN_NB; ++b) { int t = bs[b]; bs[b] = run; run += t; }
    }
    __syncthreads();
    for (int i = tid; i < N_NODES; i += 1024) offs[i] = partial[i] + bs[i >> 10];
    if (tid == 0) offs[N_NODES] = N_EDGES;
}

__global__ __launch_bounds__(256) void scatter_kernel(
    const int* __restrict__ src, const int* __restrict__ dst,
    const int* __restrict__ offs, int* __restrict__ cursor,
    int* __restrict__ perm, int* __restrict__ psrc)
{
    int e = blockIdx.x * 256 + threadIdx.x;
    if (e >= N_EDGES) return;
    int d = dst[e];
    int p = atomicAdd(&cursor[d], 1);
    int pos = offs[d] + p;
    perm[pos] = e;
    psrc[pos] = src[e];
}

// attention logits in CSR position order: 32 lanes/edge, float4 row loads
__global__ __launch_bounds__(256) void attp_kernel(
    const float* __restrict__ k, const float* __restrict__ q,
    const float* __restrict__ relw, const int* __restrict__ perm,
    const int* __restrict__ src, const int* __restrict__ dst,
    const int* __restrict__ etype, float* __restrict__ attp)
{
    const int lane = threadIdx.x & 31;
    const int i = blockIdx.x * 8 + (threadIdx.x >> 5);
    if (i >= N_EDGES) return;
    const int e = perm[i];
    const int s_ = src[e], d_ = dst[e], t_ = etype[e];
    float acc = 0.f;
    if (lane < 25) {
        const float4 kv = ((const float4*)(k + (size_t)s_ * 100))[lane];
        const float4 qv = ((const float4*)(q + (size_t)d_ * 100))[lane];
        const float4 wv = ((const float4*)(relw + t_ * 100))[lane];
        acc = kv.x * wv.x * qv.x + kv.y * wv.y * qv.y
            + kv.z * wv.z * qv.z + kv.w * wv.w * qv.w;
    }
    #pragma unroll
    for (int off = 16; off > 0; off >>= 1) acc += __shfl_xor(acc, off, 32);
    if (lane == 0) attp[i] = acc;
}

// one wave per node: softmax + weighted-V aggregate + gated combine + BN partials
__global__ __launch_bounds__(256) void agg_kernel(
    const int* __restrict__ offs, const int* __restrict__ psrc,
    const float* __restrict__ attp, const float* __restrict__ v,
    const float* __restrict__ alpha, float* __restrict__ out,
    float* __restrict__ bnpart)
{
    __shared__ float ls[100], lq[100];
    const int tid = threadIdx.x;
    if (tid < 100) { ls[tid] = 0.f; lq[tid] = 0.f; }
    __syncthreads();
    const int lane = tid & 63;
    const int gwave = blockIdx.x * 4 + (tid >> 6);
    const int nwaves = AGG_NB * 4;
    const float a = 1.f / (1.f + __expf(-alpha[0]));
    const float b = 1.f - a;
    const int cl = lane;            // lane owns columns 2cl, 2cl+1
    const bool act = (cl < 50);
    float sx = 0.f, sy = 0.f, qx = 0.f, qy = 0.f;

    for (int n = gwave; n < N_NODES; n += nwaves) {
        const int beg = offs[n], end = offs[n + 1];
        float m = -INFINITY;
        for (int i = beg + lane; i < end; i += 64) m = fmaxf(m, attp[i]);
        #pragma unroll
        for (int off = 32; off > 0; off >>= 1) m = fmaxf(m, __shfl_xor(m, off, 64));
        float ax = 0.f, ay = 0.f, wsum = 0.f;
        int i = beg;
        for (; i + 4 <= end; i += 4) {
            const int s0 = psrc[i], s1 = psrc[i + 1], s2 = psrc[i + 2], s3 = psrc[i + 3];
            const float w0 = __expf(attp[i] - m),     w1 = __expf(attp[i + 1] - m);
            const float w2 = __expf(attp[i + 2] - m), w3 = __expf(attp[i + 3] - m);
            wsum += w0 + w1 + w2 + w3;
            if (act) {
                const float2 x0 = ((const float2*)(v + (size_t)s0 * 100))[cl];
                const float2 x1 = ((const float2*)(v + (size_t)s1 * 100))[cl];
                const float2 x2 = ((const float2*)(v + (size_t)s2 * 100))[cl];
                const float2 x3 = ((const float2*)(v + (size_t)s3 * 100))[cl];
                ax += w0 * x0.x + w1 * x1.x + w2 * x2.x + w3 * x3.x;
                ay += w0 * x0.y + w1 * x1.y + w2 * x2.y + w3 * x3.y;
            }
        }
        for (; i < end; ++i) {
            const int s0 = psrc[i];
            const float w0 = __expf(attp[i] - m);
            wsum += w0;
            if (act) {
                const float2 x0 = ((const float2*)(v + (size_t)s0 * 100))[cl];
                ax += w0 * x0.x;
                ay += w0 * x0.y;
            }
        }
        const float inv = (wsum > 0.f) ? 1.f / wsum : 0.f;
        if (act) {
            float2* po = (float2*)(out + (size_t)n * 100);
            float2 cur = po[cl];
            float v0 = a * cur.x + b * ax * inv;
            float v1 = a * cur.y + b * ay * inv;
            po[cl] = make_float2(v0, v1);
            sx += v0; qx += v0 * v0;
            sy += v1; qy += v1 * v1;
        }
    }
    if (act) {
        atomicAdd(&ls[2 * cl], sx);     atomicAdd(&ls[2 * cl + 1], sy);
        atomicAdd(&lq[2 * cl], qx);     atomicAdd(&lq[2 * cl + 1], qy);
    }
    __syncthreads();
    if (tid < 100) {
        bnpart[(size_t)tid * AGG_NB + blockIdx.x]         = ls[tid];
        bnpart[(size_t)(tid + 100) * AGG_NB + blockIdx.x] = lq[tid];
    }
}

__global__ __launch_bounds__(256) void bnfin_kernel(
    const float* __restrict__ bnpart,
    const float* __restrict__ gamma, const float* __restrict__ beta,
    float* __restrict__ bnsc, float* __restrict__ bnsh)
{
    const int c = blockIdx.x * 4 + (threadIdx.x >> 6);
    const int lane = threadIdx.x & 63;
    if (c >= 100) return;
    float s = 0.f, q = 0.f;
    for (int b2 = lane; b2 < AGG_NB; b2 += 64) {
        s += bnpart[(size_t)c * AGG_NB + b2];
        q += bnpart[(size_t)(c + 100) * AGG_NB + b2];
    }
    #pragma unroll
    for (int off = 32; off > 0; off >>= 1) {
        s += __shfl_xor(s, off, 64);
        q += __shfl_xor(q, off, 64);
    }
    if (lane == 0) {
        const float inv_n = 1.f / (float)N_NODES;
        float mean = s * inv_n;
        float var = q * inv_n - mean * mean;
        float sc = gamma[c] * rsqrtf(var + BN_EPS);
        bnsc[c] = sc;
        bnsh[c] = beta[c] - mean * sc;
    }
}

__global__ __launch_bounds__(256) void apply_kernel(
    float* __restrict__ out, const float* __restrict__ bnsc,
    const float* __restrict__ bnsh)
{
    const int total4 = N_NODES * 25;
    for (int idx = blockIdx.x * 256 + threadIdx.x; idx < total4; idx += gridDim.x * 256) {
        float4* p = ((float4*)out) + idx;
        const int c = (idx % 25) * 4;
        float4 t = *p;
        t.x = tanhf(t.x * bnsc[c]     + bnsh[c]);
        t.y = tanhf(t.y * bnsc[c + 1] + bnsh[c + 1]);
        t.z = tanhf(t.z * bnsc[c + 2] + bnsh[c + 2]);
        t.w = tanhf(t.w * bnsc[c + 3] + bnsh[c + 3]);
        *p = t;
    }
}

__global__ __launch_bounds__(256) void rout_kernel(
    const float* __restrict__ rf, const float* __restrict__ Wr,
    const float* __restrict__ br, float* __restrict__ out)
{
    int o = blockIdx.x * 256 + threadIdx.x;
    if (o >= 200 * 100) return;
    int r = o / 100, c = o % 100;
    float acc = br[c];
    #pragma unroll 10
    for (int d = 0; d < 100; ++d) acc += rf[r * 100 + d] * Wr[c * 100 + d];
    out[N_NODES * 100 + o] = acc;
}

extern "C" void kernel_launch(void* const* d_in, const int* in_sizes, int n_in,
                              void* d_out, int out_size, void* d_ws, size_t ws_size,
                              hipStream_t stream) {
    const float* X     = (const float*)d_in[0];
    const float* rfeat = (const float*)d_in[1];
    const int*   src   = (const int*)d_in[2];
    const int*   dst   = (const int*)d_in[3];
    const int*   ety   = (const int*)d_in[4];
    const float* Wsw   = (const float*)d_in[6];
    const float* Wsb   = (const float*)d_in[7];
    const float* Wkw   = (const float*)d_in[8];
    const float* Wkb   = (const float*)d_in[9];
    const float* Wqw   = (const float*)d_in[10];
    const float* Wqb   = (const float*)d_in[11];
    const float* Wvw   = (const float*)d_in[12];
    const float* Wvb   = (const float*)d_in[13];
    const float* Wrw   = (const float*)d_in[14];
    const float* Wrb   = (const float*)d_in[15];
    const float* ratt  = (const float*)d_in[16];
    const float* wcomp = (const float*)d_in[17];
    const float* alpha = (const float*)d_in[18];
    const float* gamma = (const float*)d_in[20];
    const float* beta  = (const float*)d_in[21];

    float* out = (float*)d_out;
    float* ws  = (float*)d_ws;
    if (ws_size < (size_t)WS_ELEMS * sizeof(float)) return;

    float* relw   = ws + OFS_RELW;
    float* k      = ws + OFS_K;
    float* q      = ws + OFS_Q;
    float* v      = ws + OFS_V;
    float* attp   = ws + OFS_ATTP;
    float* bnpart = ws + OFS_BNPART;
    float* bnsc   = ws + OFS_BNSC;
    float* bnsh   = ws + OFS_BNSH;
    float* Wt     = ws + OFS_WT;
    int* cnt      = (int*)(ws + OFS_CNT);
    int* partial  = (int*)(ws + OFS_PART);
    int* bsum     = (int*)(ws + OFS_BSUM);
    int* offs     = (int*)(ws + OFS_OFFS);
    int* cursor   = (int*)(ws + OFS_CURS);
    int* perm     = (int*)(ws + OFS_PERM);
    int* psrc     = (int*)(ws + OFS_PSRC);

    hipMemsetAsync(cnt, 0, 50000 * sizeof(int), stream);
    hipMemsetAsync(cursor, 0, 50000 * sizeof(int), stream);

    relw_kernel<<<(20000 + 255) / 256, 256, 0, stream>>>(wcomp, ratt, relw);
    wt_kernel<<<(40000 + 255) / 256, 256, 0, stream>>>(Wkw, Wqw, Wvw, Wsw, Wt);
    proj_kernel<<<(N_NODES + 63) / 64, 256, 0, stream>>>(
        X, Wt, Wkb, Wqb, Wvb, Wsb, k, q, v, out);

    hist_kernel<<<(N_EDGES + 255) / 256, 256, 0, stream>>>(dst, cnt);
    scanA_kernel<<<SCAN_NB, 1024, 0, stream>>>(cnt, partial, bsum);
    scanB_kernel<<<1, 1024, 0, stream>>>(partial, bsum, offs);
    scatter_kernel<<<(N_EDGES + 255) / 256, 256, 0, stream>>>(src, dst, offs, cursor, perm, psrc);

    attp_kernel<<<(N_EDGES + 7) / 8, 256, 0, stream>>>(
        k, q, relw, perm, src, dst, ety, attp);
    agg_kernel<<<AGG_NB, 256, 0, stream>>>(offs, psrc, attp, v, alpha, out, bnpart);
    bnfin_kernel<<<25, 256, 0, stream>>>(bnpart, gamma, beta, bnsc, bnsh);
    apply_kernel<<<2048, 256, 0, stream>>>(out, bnsc, bnsh);
    rout_kernel<<<(20000 + 255) / 256, 256, 0, stream>>>(rfeat, Wrw, Wrb, out);
}

// Round 6
// 452.245 us; speedup vs baseline: 1.4672x; 1.4672x over previous
//
#include <hip/hip_runtime.h>
#include <hip/hip_bf16.h>
#include <math.h>

#define N_NODES 50000
#define N_EDGES 800000
#define BN_EPS  1e-5f
#define SCAN_NB 49     // ceil(50000/1024)
#define AGG_NB  2048   // agg grid blocks

// ---- workspace layout (float-element offsets) ----
#define OFS_RELW   0
#define OFS_K      20480
#define OFS_Q      (OFS_K + 5000000)
#define OFS_V      (OFS_Q + 5000000)
#define OFS_ATTP   (OFS_V + 5000000)
#define OFS_BNPART (OFS_ATTP + 800000)          // 200 * AGG_NB
#define OFS_BNSC   (OFS_BNPART + 200 * AGG_NB)
#define OFS_BNSH   (OFS_BNSC + 128)
// int region
#define OFS_CNT    (OFS_BNSH + 128)
#define OFS_PART   (OFS_CNT + 50176)
#define OFS_BSUM   (OFS_PART + 50176)
#define OFS_OFFS   (OFS_BSUM + 64)
#define OFS_CURS   (OFS_OFFS + 50176)
#define OFS_PERM   (OFS_CURS + 50176)
#define OFS_PSRC   (OFS_PERM + 800000)
#define OFS_WT     (OFS_PSRC + 800000)          // 4 * 100 * 100 transposed W
#define WS_ELEMS   (OFS_WT + 40960)

// rel_w[r][c] = sum_b w_comp[r][b] * relation_att[b][c]
__global__ __launch_bounds__(256) void relw_kernel(
    const float* __restrict__ wcomp, const float* __restrict__ ratt,
    float* __restrict__ relw)
{
    int o = blockIdx.x * 256 + threadIdx.x;
    if (o >= 200 * 100) return;
    int r = o / 100, c = o % 100;
    float acc = 0.f;
    #pragma unroll 10
    for (int b = 0; b < 50; ++b) acc += wcomp[r * 50 + b] * ratt[b * 100 + c];
    relw[o] = acc;
}

// transpose 4 projection matrices: Wt[m][d][c] = Wm[c][d]
__global__ __launch_bounds__(256) void wt_kernel(
    const float* __restrict__ Wk, const float* __restrict__ Wq,
    const float* __restrict__ Wv, const float* __restrict__ Ws,
    float* __restrict__ Wt)
{
    int o = blockIdx.x * 256 + threadIdx.x;
    if (o >= 40000) return;
    int m = o / 10000, rem = o % 10000, d = rem / 100, c = rem % 100;
    const float* W = (m == 0) ? Wk : (m == 1) ? Wq : (m == 2) ? Wv : Ws;
    Wt[o] = W[c * 100 + d];
}

// fused projections: wave w owns matrix w; lane l owns output cols (2l,2l+1),
// W slice held in VGPRs (reused for 64 nodes); X rows broadcast from LDS;
// stores fully lane-coalesced (no partial-line write amplification).
__global__ __launch_bounds__(256, 2) void proj_kernel(
    const float* __restrict__ X, const float* __restrict__ Wt,
    const float* __restrict__ bk, const float* __restrict__ bq,
    const float* __restrict__ bv, const float* __restrict__ bs,
    float* __restrict__ ko, float* __restrict__ qo,
    float* __restrict__ vo, float* __restrict__ so)
{
    __shared__ float Xs[64][100];
    const int tid = threadIdx.x;
    const int nb = blockIdx.x * 64;

    // stage X tile, perfectly coalesced (bank = tid%32, conflict-free)
    for (int idx = tid; idx < 6400; idx += 256) {
        int n = idx / 100, d = idx % 100;
        int node = nb + n;
        Xs[n][d] = (node < N_NODES) ? X[(size_t)node * 100 + d] : 0.f;
    }

    const int wid  = tid >> 6;
    const int lane = tid & 63;
    const bool act = (lane < 50);

    const float* bp = (wid == 0) ? bk : (wid == 1) ? bq : (wid == 2) ? bv : bs;
    float*       op = (wid == 0) ? ko : (wid == 1) ? qo : (wid == 2) ? vo : so;

    // W slice into registers: w[d] = Wt[wid][d][2l..2l+1]  (coalesced loads)
    float2 w[100];
    float2 bias = make_float2(0.f, 0.f);
    if (act) {
        const float* wbase = Wt + wid * 10000 + 2 * lane;
        #pragma unroll 10
        for (int d = 0; d < 100; ++d)
            w[d] = *(const float2*)(wbase + d * 100);
        bias = *(const float2*)(bp + 2 * lane);
    }
    __syncthreads();

    for (int n = 0; n < 64; ++n) {
        const int node = nb + n;
        float2 a0 = make_float2(0.f, 0.f), a1 = make_float2(0.f, 0.f);
        float2 a2 = make_float2(0.f, 0.f), a3 = make_float2(0.f, 0.f);
        #pragma unroll
        for (int d4 = 0; d4 < 25; ++d4) {
            const float4 xq = *(const float4*)&Xs[n][d4 * 4];  // wave-uniform bcast
            a0.x += xq.x * w[4 * d4 + 0].x;  a0.y += xq.x * w[4 * d4 + 0].y;
            a1.x += xq.y * w[4 * d4 + 1].x;  a1.y += xq.y * w[4 * d4 + 1].y;
            a2.x += xq.z * w[4 * d4 + 2].x;  a2.y += xq.z * w[4 * d4 + 2].y;
            a3.x += xq.w * w[4 * d4 + 3].x;  a3.y += xq.w * w[4 * d4 + 3].y;
        }
        if (act && node < N_NODES) {
            float2 r = make_float2(a0.x + a1.x + a2.x + a3.x + bias.x,
                                   a0.y + a1.y + a2.y + a3.y + bias.y);
            *(float2*)(op + (size_t)node * 100 + 2 * lane) = r;  // coalesced
        }
    }
}

__global__ __launch_bounds__(256) void hist_kernel(
    const int* __restrict__ dst, int* __restrict__ cnt)
{
    int e = blockIdx.x * 256 + threadIdx.x;
    if (e < N_EDGES) atomicAdd(&cnt[dst[e]], 1);
}

__global__ __launch_bounds__(1024) void scanA_kernel(
    const int* __restrict__ cnt, int* __restrict__ partial, int* __restrict__ bsum)
{
    __shared__ int buf[1024];
    int tid = threadIdx.x;
    int i = blockIdx.x * 1024 + tid;
    int val = (i < N_NODES) ? cnt[i] : 0;
    buf[tid] = val;
    __syncthreads();
    for (int off = 1; off < 1024; off <<= 1) {
        int t = (tid >= off) ? buf[tid - off] : 0;
        __syncthreads();
        buf[tid] += t;
        __syncthreads();
    }
    int incl = buf[tid];
    if (i < N_NODES) partial[i] = incl - val;
    if (tid == 1023) bsum[blockIdx.x] = incl;
}

__global__ __launch_bounds__(1024) void scanB_kernel(
    const int* __restrict__ partial, const int* __restrict__ bsum,
    int* __restrict__ offs)
{
    __shared__ int bs[64];
    int tid = threadIdx.x;
    if (tid < SCAN_NB) bs[tid] = bsum[tid];
    __syncthreads();
    if (tid == 0) {
        int run = 0;
        for (int b = 0; b < SCAN_NB; ++b) { int t = bs[b]; bs[b] = run; run += t; }
    }
    __syncthreads();
    for (int i = tid; i < N_NODES; i += 1024) offs[i] = partial[i] + bs[i >> 10];
    if (tid == 0) offs[N_NODES] = N_EDGES;
}

__global__ __launch_bounds__(256) void scatter_kernel(
    const int* __restrict__ src, const int* __restrict__ dst,
    const int* __restrict__ offs, int* __restrict__ cursor,
    int* __restrict__ perm, int* __restrict__ psrc)
{
    int e = blockIdx.x * 256 + threadIdx.x;
    if (e >= N_EDGES) return;
    int d = dst[e];
    int p = atomicAdd(&cursor[d], 1);
    int pos = offs[d] + p;
    perm[pos] = e;
    psrc[pos] = src[e];
}

// attention logits in CSR position order: 32 lanes/edge, float4 row loads
__global__ __launch_bounds__(256) void attp_kernel(
    const float* __restrict__ k, const float* __restrict__ q,
    const float* __restrict__ relw, const int* __restrict__ perm,
    const int* __restrict__ src, const int* __restrict__ dst,
    const int* __restrict__ etype, float* __restrict__ attp)
{
    const int lane = threadIdx.x & 31;
    const int i = blockIdx.x * 8 + (threadIdx.x >> 5);
    if (i >= N_EDGES) return;
    const int e = perm[i];
    const int s_ = src[e], d_ = dst[e], t_ = etype[e];
    float acc = 0.f;
    if (lane < 25) {
        const float4 kv = ((const float4*)(k + (size_t)s_ * 100))[lane];
        const float4 qv = ((const float4*)(q + (size_t)d_ * 100))[lane];
        const float4 wv = ((const float4*)(relw + t_ * 100))[lane];
        acc = kv.x * wv.x * qv.x + kv.y * wv.y * qv.y
            + kv.z * wv.z * qv.z + kv.w * wv.w * qv.w;
    }
    #pragma unroll
    for (int off = 16; off > 0; off >>= 1) acc += __shfl_xor(acc, off, 32);
    if (lane == 0) attp[i] = acc;
}

// one wave per node: softmax + weighted-V aggregate + gated combine + BN partials
__global__ __launch_bounds__(256) void agg_kernel(
    const int* __restrict__ offs, const int* __restrict__ psrc,
    const float* __restrict__ attp, const float* __restrict__ v,
    const float* __restrict__ alpha, float* __restrict__ out,
    float* __restrict__ bnpart)
{
    __shared__ float ls[100], lq[100];
    const int tid = threadIdx.x;
    if (tid < 100) { ls[tid] = 0.f; lq[tid] = 0.f; }
    __syncthreads();
    const int lane = tid & 63;
    const int gwave = blockIdx.x * 4 + (tid >> 6);
    const int nwaves = AGG_NB * 4;
    const float a = 1.f / (1.f + __expf(-alpha[0]));
    const float b = 1.f - a;
    const int cl = lane;            // lane owns columns 2cl, 2cl+1
    const bool act = (cl < 50);
    float sx = 0.f, sy = 0.f, qx = 0.f, qy = 0.f;

    for (int n = gwave; n < N_NODES; n += nwaves) {
        const int beg = offs[n], end = offs[n + 1];
        float m = -INFINITY;
        for (int i = beg + lane; i < end; i += 64) m = fmaxf(m, attp[i]);
        #pragma unroll
        for (int off = 32; off > 0; off >>= 1) m = fmaxf(m, __shfl_xor(m, off, 64));
        float ax = 0.f, ay = 0.f, wsum = 0.f;
        int i = beg;
        for (; i + 4 <= end; i += 4) {
            const int s0 = psrc[i], s1 = psrc[i + 1], s2 = psrc[i + 2], s3 = psrc[i + 3];
            const float w0 = __expf(attp[i] - m),     w1 = __expf(attp[i + 1] - m);
            const float w2 = __expf(attp[i + 2] - m), w3 = __expf(attp[i + 3] - m);
            wsum += w0 + w1 + w2 + w3;
            if (act) {
                const float2 x0 = ((const float2*)(v + (size_t)s0 * 100))[cl];
                const float2 x1 = ((const float2*)(v + (size_t)s1 * 100))[cl];
                const float2 x2 = ((const float2*)(v + (size_t)s2 * 100))[cl];
                const float2 x3 = ((const float2*)(v + (size_t)s3 * 100))[cl];
                ax += w0 * x0.x + w1 * x1.x + w2 * x2.x + w3 * x3.x;
                ay += w0 * x0.y + w1 * x1.y + w2 * x2.y + w3 * x3.y;
            }
        }
        for (; i < end; ++i) {
            const int s0 = psrc[i];
            const float w0 = __expf(attp[i] - m);
            wsum += w0;
            if (act) {
                const float2 x0 = ((const float2*)(v + (size_t)s0 * 100))[cl];
                ax += w0 * x0.x;
                ay += w0 * x0.y;
            }
        }
        const float inv = (wsum > 0.f) ? 1.f / wsum : 0.f;
        if (act) {
            float2* po = (float2*)(out + (size_t)n * 100);
            float2 cur = po[cl];
            float v0 = a * cur.x + b * ax * inv;
            float v1 = a * cur.y + b * ay * inv;
            po[cl] = make_float2(v0, v1);
            sx += v0; qx += v0 * v0;
            sy += v1; qy += v1 * v1;
        }
    }
    if (act) {
        atomicAdd(&ls[2 * cl], sx);     atomicAdd(&ls[2 * cl + 1], sy);
        atomicAdd(&lq[2 * cl], qx);     atomicAdd(&lq[2 * cl + 1], qy);
    }
    __syncthreads();
    if (tid < 100) {
        bnpart[(size_t)tid * AGG_NB + blockIdx.x]         = ls[tid];
        bnpart[(size_t)(tid + 100) * AGG_NB + blockIdx.x] = lq[tid];
    }
}

__global__ __launch_bounds__(256) void bnfin_kernel(
    const float* __restrict__ bnpart,
    const float* __restrict__ gamma, const float* __restrict__ beta,
    float* __restrict__ bnsc, float* __restrict__ bnsh)
{
    const int c = blockIdx.x * 4 + (threadIdx.x >> 6);
    const int lane = threadIdx.x & 63;
    if (c >= 100) return;
    float s = 0.f, q = 0.f;
    for (int b2 = lane; b2 < AGG_NB; b2 += 64) {
        s += bnpart[(size_t)c * AGG_NB + b2];
        q += bnpart[(size_t)(c + 100) * AGG_NB + b2];
    }
    #pragma unroll
    for (int off = 32; off > 0; off >>= 1) {
        s += __shfl_xor(s, off, 64);
        q += __shfl_xor(q, off, 64);
    }
    if (lane == 0) {
        const float inv_n = 1.f / (float)N_NODES;
        float mean = s * inv_n;
        float var = q * inv_n - mean * mean;
        float sc = gamma[c] * rsqrtf(var + BN_EPS);
        bnsc[c] = sc;
        bnsh[c] = beta[c] - mean * sc;
    }
}

__global__ __launch_bounds__(256) void apply_kernel(
    float* __restrict__ out, const float* __restrict__ bnsc,
    const float* __restrict__ bnsh)
{
    const int total4 = N_NODES * 25;
    for (int idx = blockIdx.x * 256 + threadIdx.x; idx < total4; idx += gridDim.x * 256) {
        float4* p = ((float4*)out) + idx;
        const int c = (idx % 25) * 4;
        float4 t = *p;
        t.x = tanhf(t.x * bnsc[c]     + bnsh[c]);
        t.y = tanhf(t.y * bnsc[c + 1] + bnsh[c + 1]);
        t.z = tanhf(t.z * bnsc[c + 2] + bnsh[c + 2]);
        t.w = tanhf(t.w * bnsc[c + 3] + bnsh[c + 3]);
        *p = t;
    }
}

__global__ __launch_bounds__(256) void rout_kernel(
    const float* __restrict__ rf, const float* __restrict__ Wr,
    const float* __restrict__ br, float* __restrict__ out)
{
    int o = blockIdx.x * 256 + threadIdx.x;
    if (o >= 200 * 100) return;
    int r = o / 100, c = o % 100;
    float acc = br[c];
    #pragma unroll 10
    for (int d = 0; d < 100; ++d) acc += rf[r * 100 + d] * Wr[c * 100 + d];
    out[N_NODES * 100 + o] = acc;
}

extern "C" void kernel_launch(void* const* d_in, const int* in_sizes, int n_in,
                              void* d_out, int out_size, void* d_ws, size_t ws_size,
                              hipStream_t stream) {
    const float* X     = (const float*)d_in[0];
    const float* rfeat = (const float*)d_in[1];
    const int*   src   = (const int*)d_in[2];
    const int*   dst   = (const int*)d_in[3];
    const int*   ety   = (const int*)d_in[4];
    const float* Wsw   = (const float*)d_in[6];
    const float* Wsb   = (const float*)d_in[7];
    const float* Wkw   = (const float*)d_in[8];
    const float* Wkb   = (const float*)d_in[9];
    const float* Wqw   = (const float*)d_in[10];
    const float* Wqb   = (const float*)d_in[11];
    const float* Wvw   = (const float*)d_in[12];
    const float* Wvb   = (const float*)d_in[13];
    const float* Wrw   = (const float*)d_in[14];
    const float* Wrb   = (const float*)d_in[15];
    const float* ratt  = (const float*)d_in[16];
    const float* wcomp = (const float*)d_in[17];
    const float* alpha = (const float*)d_in[18];
    const float* gamma = (const float*)d_in[20];
    const float* beta  = (const float*)d_in[21];

    float* out = (float*)d_out;
    float* ws  = (float*)d_ws;
    if (ws_size < (size_t)WS_ELEMS * sizeof(float)) return;

    float* relw   = ws + OFS_RELW;
    float* k      = ws + OFS_K;
    float* q      = ws + OFS_Q;
    float* v      = ws + OFS_V;
    float* attp   = ws + OFS_ATTP;
    float* bnpart = ws + OFS_BNPART;
    float* bnsc   = ws + OFS_BNSC;
    float* bnsh   = ws + OFS_BNSH;
    float* Wt     = ws + OFS_WT;
    int* cnt      = (int*)(ws + OFS_CNT);
    int* partial  = (int*)(ws + OFS_PART);
    int* bsum     = (int*)(ws + OFS_BSUM);
    int* offs     = (int*)(ws + OFS_OFFS);
    int* cursor   = (int*)(ws + OFS_CURS);
    int* perm     = (int*)(ws + OFS_PERM);
    int* psrc     = (int*)(ws + OFS_PSRC);

    hipMemsetAsync(cnt, 0, 50000 * sizeof(int), stream);
    hipMemsetAsync(cursor, 0, 50000 * sizeof(int), stream);

    relw_kernel<<<(20000 + 255) / 256, 256, 0, stream>>>(wcomp, ratt, relw);
    wt_kernel<<<(40000 + 255) / 256, 256, 0, stream>>>(Wkw, Wqw, Wvw, Wsw, Wt);
    proj_kernel<<<(N_NODES + 63) / 64, 256, 0, stream>>>(
        X, Wt, Wkb, Wqb, Wvb, Wsb, k, q, v, out);

    hist_kernel<<<(N_EDGES + 255) / 256, 256, 0, stream>>>(dst, cnt);
    scanA_kernel<<<SCAN_NB, 1024, 0, stream>>>(cnt, partial, bsum);
    scanB_kernel<<<1, 1024, 0, stream>>>(partial, bsum, offs);
    scatter_kernel<<<(N_EDGES + 255) / 256, 256, 0, stream>>>(src, dst, offs, cursor, perm, psrc);

    attp_kernel<<<(N_EDGES + 7) / 8, 256, 0, stream>>>(
        k, q, relw, perm, src, dst, ety, attp);
    agg_kernel<<<AGG_NB, 256, 0, stream>>>(offs, psrc, attp, v, alpha, out, bnpart);
    bnfin_kernel<<<25, 256, 0, stream>>>(bnpart, gamma, beta, bnsc, bnsh);
    apply_kernel<<<2048, 256, 0, stream>>>(out, bnsc, bnsh);
    rout_kernel<<<(20000 + 255) / 256, 256, 0, stream>>>(rfeat, Wrw, Wrb, out);
}

// Round 7
// 434.119 us; speedup vs baseline: 1.5285x; 1.0418x over previous
//
#include <hip/hip_runtime.h>
#include <hip/hip_bf16.h>
#include <math.h>

#define N_NODES 50000
#define N_EDGES 800000
#define BN_EPS  1e-5f
#define SCAN_NB 49     // ceil(50000/1024)
#define AGG_NB  2048   // agg grid blocks

// ---- workspace layout (float-element offsets) ----
#define OFS_RELW   0
#define OFS_K      20480
#define OFS_Q      (OFS_K + 5000000)
#define OFS_V      (OFS_Q + 5000000)
#define OFS_ATTP   (OFS_V + 5000000)
#define OFS_BNPART (OFS_ATTP + 800000)          // 200 * AGG_NB
#define OFS_BNSC   (OFS_BNPART + 200 * AGG_NB)
#define OFS_BNSH   (OFS_BNSC + 128)
// int region
#define OFS_CNT    (OFS_BNSH + 128)
#define OFS_PART   (OFS_CNT + 50176)
#define OFS_BSUM   (OFS_PART + 50176)
#define OFS_OFFS   (OFS_BSUM + 64)
#define OFS_CURS   (OFS_OFFS + 50176)
#define OFS_PERM   (OFS_CURS + 50176)
#define OFS_PSRC   (OFS_PERM + 800000)
#define OFS_WT     (OFS_PSRC + 800000)          // 4 * 100 * 100 transposed W
#define WS_ELEMS   (OFS_WT + 40960)

// rel_w[r][c] = sum_b w_comp[r][b] * relation_att[b][c]
__global__ __launch_bounds__(256) void relw_kernel(
    const float* __restrict__ wcomp, const float* __restrict__ ratt,
    float* __restrict__ relw)
{
    int o = blockIdx.x * 256 + threadIdx.x;
    if (o >= 200 * 100) return;
    int r = o / 100, c = o % 100;
    float acc = 0.f;
    #pragma unroll 10
    for (int b = 0; b < 50; ++b) acc += wcomp[r * 50 + b] * ratt[b * 100 + c];
    relw[o] = acc;
}

// transpose 4 projection matrices: Wt[m][d][c] = Wm[c][d]
__global__ __launch_bounds__(256) void wt_kernel(
    const float* __restrict__ Wk, const float* __restrict__ Wq,
    const float* __restrict__ Wv, const float* __restrict__ Ws,
    float* __restrict__ Wt)
{
    int o = blockIdx.x * 256 + threadIdx.x;
    if (o >= 40000) return;
    int m = o / 10000, rem = o % 10000, d = rem / 100, c = rem % 100;
    const float* W = (m == 0) ? Wk : (m == 1) ? Wq : (m == 2) ? Wv : Ws;
    Wt[o] = W[c * 100 + d];
}

// fused projections: 512 threads = 8 waves; wave pair (2m,2m+1) owns matrix m;
// lane owns ONE output column (wave 2m: cols 0..63, wave 2m+1: cols 64..99).
// W column slice in float4 wreg[25] (static unroll -> VGPRs, no scratch);
// X staged in LDS, read as wave-uniform b128 broadcasts; stores coalesced.
__global__ __launch_bounds__(512) void proj_kernel(
    const float* __restrict__ X, const float* __restrict__ Wt,
    const float* __restrict__ bk, const float* __restrict__ bq,
    const float* __restrict__ bv, const float* __restrict__ bs,
    float* __restrict__ ko, float* __restrict__ qo,
    float* __restrict__ vo, float* __restrict__ so)
{
    __shared__ float Xs[64][100];
    const int tid = threadIdx.x;
    const int nb = blockIdx.x * 64;

    // stage X tile: 1600 float4, coalesced
    for (int idx = tid; idx < 1600; idx += 512) {
        int n = idx / 25, c4 = idx % 25;
        int node = nb + n;
        float4 x = (node < N_NODES)
                   ? ((const float4*)(X + (size_t)node * 100))[c4]
                   : make_float4(0.f, 0.f, 0.f, 0.f);
        *(float4*)&Xs[n][c4 * 4] = x;
    }

    const int wv   = tid >> 6;
    const int lane = tid & 63;
    const int m    = wv >> 1;          // matrix id
    const int c    = (wv & 1) * 64 + lane;   // output column
    const bool act = (c < 100);

    const float* bp = (m == 0) ? bk : (m == 1) ? bq : (m == 2) ? bv : bs;
    float*       op = (m == 0) ? ko : (m == 1) ? qo : (m == 2) ? vo : so;

    float4 wreg[25];
    float bias = 0.f;
    if (act) {
        const float* wb = Wt + m * 10000 + c;    // Wt[m][d][c], d-stride 100
        #pragma unroll
        for (int d4 = 0; d4 < 25; ++d4) {
            wreg[d4].x = wb[(4 * d4 + 0) * 100];
            wreg[d4].y = wb[(4 * d4 + 1) * 100];
            wreg[d4].z = wb[(4 * d4 + 2) * 100];
            wreg[d4].w = wb[(4 * d4 + 3) * 100];
        }
        bias = bp[c];
    }
    __syncthreads();

    const int nmax = min(64, N_NODES - nb);
    for (int n = 0; n < nmax; ++n) {
        float acc = 0.f;
        #pragma unroll
        for (int d4 = 0; d4 < 25; ++d4) {
            const float4 xq = *(const float4*)&Xs[n][d4 * 4];   // uniform bcast
            acc += xq.x * wreg[d4].x + xq.y * wreg[d4].y
                 + xq.z * wreg[d4].z + xq.w * wreg[d4].w;
        }
        if (act)
            op[(size_t)(nb + n) * 100 + c] = acc + bias;        // coalesced 4B
    }
}

__global__ __launch_bounds__(256) void hist_kernel(
    const int* __restrict__ dst, int* __restrict__ cnt)
{
    int e = blockIdx.x * 256 + threadIdx.x;
    if (e < N_EDGES) atomicAdd(&cnt[dst[e]], 1);
}

__global__ __launch_bounds__(1024) void scanA_kernel(
    const int* __restrict__ cnt, int* __restrict__ partial, int* __restrict__ bsum)
{
    __shared__ int buf[1024];
    int tid = threadIdx.x;
    int i = blockIdx.x * 1024 + tid;
    int val = (i < N_NODES) ? cnt[i] : 0;
    buf[tid] = val;
    __syncthreads();
    for (int off = 1; off < 1024; off <<= 1) {
        int t = (tid >= off) ? buf[tid - off] : 0;
        __syncthreads();
        buf[tid] += t;
        __syncthreads();
    }
    int incl = buf[tid];
    if (i < N_NODES) partial[i] = incl - val;
    if (tid == 1023) bsum[blockIdx.x] = incl;
}

__global__ __launch_bounds__(1024) void scanB_kernel(
    const int* __restrict__ partial, const int* __restrict__ bsum,
    int* __restrict__ offs)
{
    __shared__ int bs[64];
    int tid = threadIdx.x;
    if (tid < SCAN_NB) bs[tid] = bsum[tid];
    __syncthreads();
    if (tid == 0) {
        int run = 0;
        for (int b = 0; b < SCAN_NB; ++b) { int t = bs[b]; bs[b] = run; run += t; }
    }
    __syncthreads();
    for (int i = tid; i < N_NODES; i += 1024) offs[i] = partial[i] + bs[i >> 10];
    if (tid == 0) offs[N_NODES] = N_EDGES;
}

__global__ __launch_bounds__(256) void scatter_kernel(
    const int* __restrict__ src, const int* __restrict__ dst,
    const int* __restrict__ offs, int* __restrict__ cursor,
    int* __restrict__ perm, int* __restrict__ psrc)
{
    int e = blockIdx.x * 256 + threadIdx.x;
    if (e >= N_EDGES) return;
    int d = dst[e];
    int p = atomicAdd(&cursor[d], 1);
    int pos = offs[d] + p;
    perm[pos] = e;
    psrc[pos] = src[e];
}

// attention logits in CSR position order: 32 lanes/edge, float4 row loads
__global__ __launch_bounds__(256) void attp_kernel(
    const float* __restrict__ k, const float* __restrict__ q,
    const float* __restrict__ relw, const int* __restrict__ perm,
    const int* __restrict__ src, const int* __restrict__ dst,
    const int* __restrict__ etype, float* __restrict__ attp)
{
    const int lane = threadIdx.x & 31;
    const int i = blockIdx.x * 8 + (threadIdx.x >> 5);
    if (i >= N_EDGES) return;
    const int e = perm[i];
    const int s_ = src[e], d_ = dst[e], t_ = etype[e];
    float acc = 0.f;
    if (lane < 25) {
        const float4 kv = ((const float4*)(k + (size_t)s_ * 100))[lane];
        const float4 qv = ((const float4*)(q + (size_t)d_ * 100))[lane];
        const float4 wv = ((const float4*)(relw + t_ * 100))[lane];
        acc = kv.x * wv.x * qv.x + kv.y * wv.y * qv.y
            + kv.z * wv.z * qv.z + kv.w * wv.w * qv.w;
    }
    #pragma unroll
    for (int off = 16; off > 0; off >>= 1) acc += __shfl_xor(acc, off, 32);
    if (lane == 0) attp[i] = acc;
}

// one wave per node: softmax + weighted-V aggregate + gated combine + BN partials
__global__ __launch_bounds__(256) void agg_kernel(
    const int* __restrict__ offs, const int* __restrict__ psrc,
    const float* __restrict__ attp, const float* __restrict__ v,
    const float* __restrict__ alpha, float* __restrict__ out,
    float* __restrict__ bnpart)
{
    __shared__ float ls[100], lq[100];
    const int tid = threadIdx.x;
    if (tid < 100) { ls[tid] = 0.f; lq[tid] = 0.f; }
    __syncthreads();
    const int lane = tid & 63;
    const int gwave = blockIdx.x * 4 + (tid >> 6);
    const int nwaves = AGG_NB * 4;
    const float a = 1.f / (1.f + __expf(-alpha[0]));
    const float b = 1.f - a;
    const int cl = lane;            // lane owns columns 2cl, 2cl+1
    const bool act = (cl < 50);
    float sx = 0.f, sy = 0.f, qx = 0.f, qy = 0.f;

    for (int n = gwave; n < N_NODES; n += nwaves) {
        const int beg = offs[n], end = offs[n + 1];
        float m = -INFINITY;
        for (int i = beg + lane; i < end; i += 64) m = fmaxf(m, attp[i]);
        #pragma unroll
        for (int off = 32; off > 0; off >>= 1) m = fmaxf(m, __shfl_xor(m, off, 64));
        float ax = 0.f, ay = 0.f, wsum = 0.f;
        int i = beg;
        for (; i + 4 <= end; i += 4) {
            const int s0 = psrc[i], s1 = psrc[i + 1], s2 = psrc[i + 2], s3 = psrc[i + 3];
            const float w0 = __expf(attp[i] - m),     w1 = __expf(attp[i + 1] - m);
            const float w2 = __expf(attp[i + 2] - m), w3 = __expf(attp[i + 3] - m);
            wsum += w0 + w1 + w2 + w3;
            if (act) {
                const float2 x0 = ((const float2*)(v + (size_t)s0 * 100))[cl];
                const float2 x1 = ((const float2*)(v + (size_t)s1 * 100))[cl];
                const float2 x2 = ((const float2*)(v + (size_t)s2 * 100))[cl];
                const float2 x3 = ((const float2*)(v + (size_t)s3 * 100))[cl];
                ax += w0 * x0.x + w1 * x1.x + w2 * x2.x + w3 * x3.x;
                ay += w0 * x0.y + w1 * x1.y + w2 * x2.y + w3 * x3.y;
            }
        }
        for (; i < end; ++i) {
            const int s0 = psrc[i];
            const float w0 = __expf(attp[i] - m);
            wsum += w0;
            if (act) {
                const float2 x0 = ((const float2*)(v + (size_t)s0 * 100))[cl];
                ax += w0 * x0.x;
                ay += w0 * x0.y;
            }
        }
        const float inv = (wsum > 0.f) ? 1.f / wsum : 0.f;
        if (act) {
            float2* po = (float2*)(out + (size_t)n * 100);
            float2 cur = po[cl];
            float v0 = a * cur.x + b * ax * inv;
            float v1 = a * cur.y + b * ay * inv;
            po[cl] = make_float2(v0, v1);
            sx += v0; qx += v0 * v0;
            sy += v1; qy += v1 * v1;
        }
    }
    if (act) {
        atomicAdd(&ls[2 * cl], sx);     atomicAdd(&ls[2 * cl + 1], sy);
        atomicAdd(&lq[2 * cl], qx);     atomicAdd(&lq[2 * cl + 1], qy);
    }
    __syncthreads();
    if (tid < 100) {
        bnpart[(size_t)tid * AGG_NB + blockIdx.x]         = ls[tid];
        bnpart[(size_t)(tid + 100) * AGG_NB + blockIdx.x] = lq[tid];
    }
}

__global__ __launch_bounds__(256) void bnfin_kernel(
    const float* __restrict__ bnpart,
    const float* __restrict__ gamma, const float* __restrict__ beta,
    float* __restrict__ bnsc, float* __restrict__ bnsh)
{
    const int c = blockIdx.x * 4 + (threadIdx.x >> 6);
    const int lane = threadIdx.x & 63;
    if (c >= 100) return;
    float s = 0.f, q = 0.f;
    for (int b2 = lane; b2 < AGG_NB; b2 += 64) {
        s += bnpart[(size_t)c * AGG_NB + b2];
        q += bnpart[(size_t)(c + 100) * AGG_NB + b2];
    }
    #pragma unroll
    for (int off = 32; off > 0; off >>= 1) {
        s += __shfl_xor(s, off, 64);
        q += __shfl_xor(q, off, 64);
    }
    if (lane == 0) {
        const float inv_n = 1.f / (float)N_NODES;
        float mean = s * inv_n;
        float var = q * inv_n - mean * mean;
        float sc = gamma[c] * rsqrtf(var + BN_EPS);
        bnsc[c] = sc;
        bnsh[c] = beta[c] - mean * sc;
    }
}

__global__ __launch_bounds__(256) void apply_kernel(
    float* __restrict__ out, const float* __restrict__ bnsc,
    const float* __restrict__ bnsh)
{
    const int total4 = N_NODES * 25;
    for (int idx = blockIdx.x * 256 + threadIdx.x; idx < total4; idx += gridDim.x * 256) {
        float4* p = ((float4*)out) + idx;
        const int c = (idx % 25) * 4;
        float4 t = *p;
        t.x = tanhf(t.x * bnsc[c]     + bnsh[c]);
        t.y = tanhf(t.y * bnsc[c + 1] + bnsh[c + 1]);
        t.z = tanhf(t.z * bnsc[c + 2] + bnsh[c + 2]);
        t.w = tanhf(t.w * bnsc[c + 3] + bnsh[c + 3]);
        *p = t;
    }
}

__global__ __launch_bounds__(256) void rout_kernel(
    const float* __restrict__ rf, const float* __restrict__ Wr,
    const float* __restrict__ br, float* __restrict__ out)
{
    int o = blockIdx.x * 256 + threadIdx.x;
    if (o >= 200 * 100) return;
    int r = o / 100, c = o % 100;
    float acc = br[c];
    #pragma unroll 10
    for (int d = 0; d < 100; ++d) acc += rf[r * 100 + d] * Wr[c * 100 + d];
    out[N_NODES * 100 + o] = acc;
}

extern "C" void kernel_launch(void* const* d_in, const int* in_sizes, int n_in,
                              void* d_out, int out_size, void* d_ws, size_t ws_size,
                              hipStream_t stream) {
    const float* X     = (const float*)d_in[0];
    const float* rfeat = (const float*)d_in[1];
    const int*   src   = (const int*)d_in[2];
    const int*   dst   = (const int*)d_in[3];
    const int*   ety   = (const int*)d_in[4];
    const float* Wsw   = (const float*)d_in[6];
    const float* Wsb   = (const float*)d_in[7];
    const float* Wkw   = (const float*)d_in[8];
    const float* Wkb   = (const float*)d_in[9];
    const float* Wqw   = (const float*)d_in[10];
    const float* Wqb   = (const float*)d_in[11];
    const float* Wvw   = (const float*)d_in[12];
    const float* Wvb   = (const float*)d_in[13];
    const float* Wrw   = (const float*)d_in[14];
    const float* Wrb   = (const float*)d_in[15];
    const float* ratt  = (const float*)d_in[16];
    const float* wcomp = (const float*)d_in[17];
    const float* alpha = (const float*)d_in[18];
    const float* gamma = (const float*)d_in[20];
    const float* beta  = (const float*)d_in[21];

    float* out = (float*)d_out;
    float* ws  = (float*)d_ws;
    if (ws_size < (size_t)WS_ELEMS * sizeof(float)) return;

    float* relw   = ws + OFS_RELW;
    float* k      = ws + OFS_K;
    float* q      = ws + OFS_Q;
    float* v      = ws + OFS_V;
    float* attp   = ws + OFS_ATTP;
    float* bnpart = ws + OFS_BNPART;
    float* bnsc   = ws + OFS_BNSC;
    float* bnsh   = ws + OFS_BNSH;
    float* Wt     = ws + OFS_WT;
    int* cnt      = (int*)(ws + OFS_CNT);
    int* partial  = (int*)(ws + OFS_PART);
    int* bsum     = (int*)(ws + OFS_BSUM);
    int* offs     = (int*)(ws + OFS_OFFS);
    int* cursor   = (int*)(ws + OFS_CURS);
    int* perm     = (int*)(ws + OFS_PERM);
    int* psrc     = (int*)(ws + OFS_PSRC);

    hipMemsetAsync(cnt, 0, 50000 * sizeof(int), stream);
    hipMemsetAsync(cursor, 0, 50000 * sizeof(int), stream);

    relw_kernel<<<(20000 + 255) / 256, 256, 0, stream>>>(wcomp, ratt, relw);
    wt_kernel<<<(40000 + 255) / 256, 256, 0, stream>>>(Wkw, Wqw, Wvw, Wsw, Wt);
    proj_kernel<<<(N_NODES + 63) / 64, 512, 0, stream>>>(
        X, Wt, Wkb, Wqb, Wvb, Wsb, k, q, v, out);

    hist_kernel<<<(N_EDGES + 255) / 256, 256, 0, stream>>>(dst, cnt);
    scanA_kernel<<<SCAN_NB, 1024, 0, stream>>>(cnt, partial, bsum);
    scanB_kernel<<<1, 1024, 0, stream>>>(partial, bsum, offs);
    scatter_kernel<<<(N_EDGES + 255) / 256, 256, 0, stream>>>(src, dst, offs, cursor, perm, psrc);

    attp_kernel<<<(N_EDGES + 7) / 8, 256, 0, stream>>>(
        k, q, relw, perm, src, dst, ety, attp);
    agg_kernel<<<AGG_NB, 256, 0, stream>>>(offs, psrc, attp, v, alpha, out, bnpart);
    bnfin_kernel<<<25, 256, 0, stream>>>(bnpart, gamma, beta, bnsc, bnsh);
    apply_kernel<<<2048, 256, 0, stream>>>(out, bnsc, bnsh);
    rout_kernel<<<(20000 + 255) / 256, 256, 0, stream>>>(rfeat, Wrw, Wrb, out);
}

// Round 8
// 431.280 us; speedup vs baseline: 1.5385x; 1.0066x over previous
//
#include <hip/hip_runtime.h>
#include <hip/hip_bf16.h>
#include <math.h>

#define N_NODES 50000
#define N_EDGES 800000
#define BN_EPS  1e-5f
#define SCAN_NB 49     // ceil(50000/1024)
#define AGG_NB  2048   // agg grid blocks

// ---- workspace layout (float-element offsets) ----
#define OFS_RELW   0
#define OFS_K      20480
#define OFS_Q      (OFS_K + 5000000)
#define OFS_V      (OFS_Q + 5000000)
#define OFS_ATTP   (OFS_V + 5000000)
#define OFS_BNPART (OFS_ATTP + 800000)          // 200 * AGG_NB
#define OFS_BNSC   (OFS_BNPART + 200 * AGG_NB)
#define OFS_BNSH   (OFS_BNSC + 128)
// int region
#define OFS_CNT    (OFS_BNSH + 128)
#define OFS_PART   (OFS_CNT + 50176)
#define OFS_BSUM   (OFS_PART + 50176)
#define OFS_OFFS   (OFS_BSUM + 64)
#define OFS_CURS   (OFS_OFFS + 50176)
#define OFS_PERM   (OFS_CURS + 50176)
#define OFS_PSRC   (OFS_PERM + 800000)
#define OFS_WT     (OFS_PSRC + 800000)          // 4 * 100 * 100 transposed W
#define WS_ELEMS   (OFS_WT + 40960)

// rel_w[r][c] = sum_b w_comp[r][b] * relation_att[b][c]
__global__ __launch_bounds__(256) void relw_kernel(
    const float* __restrict__ wcomp, const float* __restrict__ ratt,
    float* __restrict__ relw)
{
    int o = blockIdx.x * 256 + threadIdx.x;
    if (o >= 200 * 100) return;
    int r = o / 100, c = o % 100;
    float acc = 0.f;
    #pragma unroll 10
    for (int b = 0; b < 50; ++b) acc += wcomp[r * 50 + b] * ratt[b * 100 + c];
    relw[o] = acc;
}

// transpose 4 projection matrices: Wt[m][d][c] = Wm[c][d]
__global__ __launch_bounds__(256) void wt_kernel(
    const float* __restrict__ Wk, const float* __restrict__ Wq,
    const float* __restrict__ Wv, const float* __restrict__ Ws,
    float* __restrict__ Wt)
{
    int o = blockIdx.x * 256 + threadIdx.x;
    if (o >= 40000) return;
    int m = o / 10000, rem = o % 10000, d = rem / 100, c = rem % 100;
    const float* W = (m == 0) ? Wk : (m == 1) ? Wq : (m == 2) ? Wv : Ws;
    Wt[o] = W[c * 100 + d];
}

// fused projections: 256 threads = 4 waves; blockIdx.y = matrix m.
// wave pair splits nodes (0-31 / 32-63); within pair, wave covers cols 0-63
// or 64-99. W column slice in float4 wreg[25] (static -> VGPRs; launch
// bounds (256,3) cap VGPR at ~170 so it stays resident). X broadcast from
// LDS; stores 4B lane-coalesced.
__global__ __launch_bounds__(256, 3) void proj_kernel(
    const float* __restrict__ X, const float* __restrict__ Wt,
    const float* __restrict__ bk, const float* __restrict__ bq,
    const float* __restrict__ bv, const float* __restrict__ bs,
    float* __restrict__ ko, float* __restrict__ qo,
    float* __restrict__ vo, float* __restrict__ so)
{
    __shared__ float Xs[64][100];
    const int tid = threadIdx.x;
    const int nb = blockIdx.x * 64;
    const int m  = blockIdx.y;

    // stage X tile: 1600 float4, coalesced
    for (int idx = tid; idx < 1600; idx += 256) {
        int n = idx / 25, c4 = idx % 25;
        int node = nb + n;
        float4 x = (node < N_NODES)
                   ? ((const float4*)(X + (size_t)node * 100))[c4]
                   : make_float4(0.f, 0.f, 0.f, 0.f);
        *(float4*)&Xs[n][c4 * 4] = x;
    }

    const int wv   = tid >> 6;
    const int lane = tid & 63;
    const int nodebase = (wv >> 1) * 32;       // 0 or 32
    const int c    = (wv & 1) * 64 + lane;     // output column
    const bool act = (c < 100);

    const float* bp = (m == 0) ? bk : (m == 1) ? bq : (m == 2) ? bv : bs;
    float*       op = (m == 0) ? ko : (m == 1) ? qo : (m == 2) ? vo : so;

    float4 wreg[25];
    float bias = 0.f;
    if (act) {
        const float* wb = Wt + m * 10000 + c;    // Wt[m][d][c], d-stride 100
        #pragma unroll
        for (int d4 = 0; d4 < 25; ++d4) {
            wreg[d4].x = wb[(4 * d4 + 0) * 100];
            wreg[d4].y = wb[(4 * d4 + 1) * 100];
            wreg[d4].z = wb[(4 * d4 + 2) * 100];
            wreg[d4].w = wb[(4 * d4 + 3) * 100];
        }
        bias = bp[c];
    }
    __syncthreads();

    #pragma unroll 2
    for (int n = 0; n < 32; ++n) {
        const int node = nb + nodebase + n;
        float acc = 0.f;
        #pragma unroll
        for (int d4 = 0; d4 < 25; ++d4) {
            const float4 xq = *(const float4*)&Xs[nodebase + n][d4 * 4]; // bcast
            acc += xq.x * wreg[d4].x + xq.y * wreg[d4].y
                 + xq.z * wreg[d4].z + xq.w * wreg[d4].w;
        }
        if (act && node < N_NODES)
            op[(size_t)node * 100 + c] = acc + bias;        // coalesced 4B
    }
}

__global__ __launch_bounds__(256) void hist_kernel(
    const int* __restrict__ dst, int* __restrict__ cnt)
{
    int e = blockIdx.x * 256 + threadIdx.x;
    if (e < N_EDGES) atomicAdd(&cnt[dst[e]], 1);
}

__global__ __launch_bounds__(1024) void scanA_kernel(
    const int* __restrict__ cnt, int* __restrict__ partial, int* __restrict__ bsum)
{
    __shared__ int buf[1024];
    int tid = threadIdx.x;
    int i = blockIdx.x * 1024 + tid;
    int val = (i < N_NODES) ? cnt[i] : 0;
    buf[tid] = val;
    __syncthreads();
    for (int off = 1; off < 1024; off <<= 1) {
        int t = (tid >= off) ? buf[tid - off] : 0;
        __syncthreads();
        buf[tid] += t;
        __syncthreads();
    }
    int incl = buf[tid];
    if (i < N_NODES) partial[i] = incl - val;
    if (tid == 1023) bsum[blockIdx.x] = incl;
}

__global__ __launch_bounds__(1024) void scanB_kernel(
    const int* __restrict__ partial, const int* __restrict__ bsum,
    int* __restrict__ offs)
{
    __shared__ int bs[64];
    int tid = threadIdx.x;
    if (tid < SCAN_NB) bs[tid] = bsum[tid];
    __syncthreads();
    if (tid == 0) {
        int run = 0;
        for (int b = 0; b < SCAN_NB; ++b) { int t = bs[b]; bs[b] = run; run += t; }
    }
    __syncthreads();
    for (int i = tid; i < N_NODES; i += 1024) offs[i] = partial[i] + bs[i >> 10];
    if (tid == 0) offs[N_NODES] = N_EDGES;
}

__global__ __launch_bounds__(256) void scatter_kernel(
    const int* __restrict__ src, const int* __restrict__ dst,
    const int* __restrict__ offs, int* __restrict__ cursor,
    int* __restrict__ perm, int* __restrict__ psrc)
{
    int e = blockIdx.x * 256 + threadIdx.x;
    if (e >= N_EDGES) return;
    int d = dst[e];
    int p = atomicAdd(&cursor[d], 1);
    int pos = offs[d] + p;
    perm[pos] = e;
    psrc[pos] = src[e];
}

// attention logits in CSR position order: 32 lanes/edge, float4 row loads
__global__ __launch_bounds__(256) void attp_kernel(
    const float* __restrict__ k, const float* __restrict__ q,
    const float* __restrict__ relw, const int* __restrict__ perm,
    const int* __restrict__ src, const int* __restrict__ dst,
    const int* __restrict__ etype, float* __restrict__ attp)
{
    const int lane = threadIdx.x & 31;
    const int i = blockIdx.x * 8 + (threadIdx.x >> 5);
    if (i >= N_EDGES) return;
    const int e = perm[i];
    const int s_ = src[e], d_ = dst[e], t_ = etype[e];
    float acc = 0.f;
    if (lane < 25) {
        const float4 kv = ((const float4*)(k + (size_t)s_ * 100))[lane];
        const float4 qv = ((const float4*)(q + (size_t)d_ * 100))[lane];
        const float4 wv = ((const float4*)(relw + t_ * 100))[lane];
        acc = kv.x * wv.x * qv.x + kv.y * wv.y * qv.y
            + kv.z * wv.z * qv.z + kv.w * wv.w * qv.w;
    }
    #pragma unroll
    for (int off = 16; off > 0; off >>= 1) acc += __shfl_xor(acc, off, 32);
    if (lane == 0) attp[i] = acc;
}

// one wave per node: softmax + weighted-V aggregate + gated combine + BN partials
__global__ __launch_bounds__(256) void agg_kernel(
    const int* __restrict__ offs, const int* __restrict__ psrc,
    const float* __restrict__ attp, const float* __restrict__ v,
    const float* __restrict__ alpha, float* __restrict__ out,
    float* __restrict__ bnpart)
{
    __shared__ float ls[100], lq[100];
    const int tid = threadIdx.x;
    if (tid < 100) { ls[tid] = 0.f; lq[tid] = 0.f; }
    __syncthreads();
    const int lane = tid & 63;
    const int gwave = blockIdx.x * 4 + (tid >> 6);
    const int nwaves = AGG_NB * 4;
    const float a = 1.f / (1.f + __expf(-alpha[0]));
    const float b = 1.f - a;
    const int cl = lane;            // lane owns columns 2cl, 2cl+1
    const bool act = (cl < 50);
    float sx = 0.f, sy = 0.f, qx = 0.f, qy = 0.f;

    for (int n = gwave; n < N_NODES; n += nwaves) {
        const int beg = offs[n], end = offs[n + 1];
        float m = -INFINITY;
        for (int i = beg + lane; i < end; i += 64) m = fmaxf(m, attp[i]);
        #pragma unroll
        for (int off = 32; off > 0; off >>= 1) m = fmaxf(m, __shfl_xor(m, off, 64));
        float ax = 0.f, ay = 0.f, wsum = 0.f;
        int i = beg;
        for (; i + 4 <= end; i += 4) {
            const int s0 = psrc[i], s1 = psrc[i + 1], s2 = psrc[i + 2], s3 = psrc[i + 3];
            const float w0 = __expf(attp[i] - m),     w1 = __expf(attp[i + 1] - m);
            const float w2 = __expf(attp[i + 2] - m), w3 = __expf(attp[i + 3] - m);
            wsum += w0 + w1 + w2 + w3;
            if (act) {
                const float2 x0 = ((const float2*)(v + (size_t)s0 * 100))[cl];
                const float2 x1 = ((const float2*)(v + (size_t)s1 * 100))[cl];
                const float2 x2 = ((const float2*)(v + (size_t)s2 * 100))[cl];
                const float2 x3 = ((const float2*)(v + (size_t)s3 * 100))[cl];
                ax += w0 * x0.x + w1 * x1.x + w2 * x2.x + w3 * x3.x;
                ay += w0 * x0.y + w1 * x1.y + w2 * x2.y + w3 * x3.y;
            }
        }
        for (; i < end; ++i) {
            const int s0 = psrc[i];
            const float w0 = __expf(attp[i] - m);
            wsum += w0;
            if (act) {
                const float2 x0 = ((const float2*)(v + (size_t)s0 * 100))[cl];
                ax += w0 * x0.x;
                ay += w0 * x0.y;
            }
        }
        const float inv = (wsum > 0.f) ? 1.f / wsum : 0.f;
        if (act) {
            float2* po = (float2*)(out + (size_t)n * 100);
            float2 cur = po[cl];
            float v0 = a * cur.x + b * ax * inv;
            float v1 = a * cur.y + b * ay * inv;
            po[cl] = make_float2(v0, v1);
            sx += v0; qx += v0 * v0;
            sy += v1; qy += v1 * v1;
        }
    }
    if (act) {
        atomicAdd(&ls[2 * cl], sx);     atomicAdd(&ls[2 * cl + 1], sy);
        atomicAdd(&lq[2 * cl], qx);     atomicAdd(&lq[2 * cl + 1], qy);
    }
    __syncthreads();
    if (tid < 100) {
        bnpart[(size_t)tid * AGG_NB + blockIdx.x]         = ls[tid];
        bnpart[(size_t)(tid + 100) * AGG_NB + blockIdx.x] = lq[tid];
    }
}

__global__ __launch_bounds__(256) void bnfin_kernel(
    const float* __restrict__ bnpart,
    const float* __restrict__ gamma, const float* __restrict__ beta,
    float* __restrict__ bnsc, float* __restrict__ bnsh)
{
    const int c = blockIdx.x * 4 + (threadIdx.x >> 6);
    const int lane = threadIdx.x & 63;
    if (c >= 100) return;
    float s = 0.f, q = 0.f;
    for (int b2 = lane; b2 < AGG_NB; b2 += 64) {
        s += bnpart[(size_t)c * AGG_NB + b2];
        q += bnpart[(size_t)(c + 100) * AGG_NB + b2];
    }
    #pragma unroll
    for (int off = 32; off > 0; off >>= 1) {
        s += __shfl_xor(s, off, 64);
        q += __shfl_xor(q, off, 64);
    }
    if (lane == 0) {
        const float inv_n = 1.f / (float)N_NODES;
        float mean = s * inv_n;
        float var = q * inv_n - mean * mean;
        float sc = gamma[c] * rsqrtf(var + BN_EPS);
        bnsc[c] = sc;
        bnsh[c] = beta[c] - mean * sc;
    }
}

__global__ __launch_bounds__(256) void apply_kernel(
    float* __restrict__ out, const float* __restrict__ bnsc,
    const float* __restrict__ bnsh)
{
    const int total4 = N_NODES * 25;
    for (int idx = blockIdx.x * 256 + threadIdx.x; idx < total4; idx += gridDim.x * 256) {
        float4* p = ((float4*)out) + idx;
        const int c = (idx % 25) * 4;
        float4 t = *p;
        t.x = tanhf(t.x * bnsc[c]     + bnsh[c]);
        t.y = tanhf(t.y * bnsc[c + 1] + bnsh[c + 1]);
        t.z = tanhf(t.z * bnsc[c + 2] + bnsh[c + 2]);
        t.w = tanhf(t.w * bnsc[c + 3] + bnsh[c + 3]);
        *p = t;
    }
}

__global__ __launch_bounds__(256) void rout_kernel(
    const float* __restrict__ rf, const float* __restrict__ Wr,
    const float* __restrict__ br, float* __restrict__ out)
{
    int o = blockIdx.x * 256 + threadIdx.x;
    if (o >= 200 * 100) return;
    int r = o / 100, c = o % 100;
    float acc = br[c];
    #pragma unroll 10
    for (int d = 0; d < 100; ++d) acc += rf[r * 100 + d] * Wr[c * 100 + d];
    out[N_NODES * 100 + o] = acc;
}

extern "C" void kernel_launch(void* const* d_in, const int* in_sizes, int n_in,
                              void* d_out, int out_size, void* d_ws, size_t ws_size,
                              hipStream_t stream) {
    const float* X     = (const float*)d_in[0];
    const float* rfeat = (const float*)d_in[1];
    const int*   src   = (const int*)d_in[2];
    const int*   dst   = (const int*)d_in[3];
    const int*   ety   = (const int*)d_in[4];
    const float* Wsw   = (const float*)d_in[6];
    const float* Wsb   = (const float*)d_in[7];
    const float* Wkw   = (const float*)d_in[8];
    const float* Wkb   = (const float*)d_in[9];
    const float* Wqw   = (const float*)d_in[10];
    const float* Wqb   = (const float*)d_in[11];
    const float* Wvw   = (const float*)d_in[12];
    const float* Wvb   = (const float*)d_in[13];
    const float* Wrw   = (const float*)d_in[14];
    const float* Wrb   = (const float*)d_in[15];
    const float* ratt  = (const float*)d_in[16];
    const float* wcomp = (const float*)d_in[17];
    const float* alpha = (const float*)d_in[18];
    const float* gamma = (const float*)d_in[20];
    const float* beta  = (const float*)d_in[21];

    float* out = (float*)d_out;
    float* ws  = (float*)d_ws;
    if (ws_size < (size_t)WS_ELEMS * sizeof(float)) return;

    float* relw   = ws + OFS_RELW;
    float* k      = ws + OFS_K;
    float* q      = ws + OFS_Q;
    float* v      = ws + OFS_V;
    float* attp   = ws + OFS_ATTP;
    float* bnpart = ws + OFS_BNPART;
    float* bnsc   = ws + OFS_BNSC;
    float* bnsh   = ws + OFS_BNSH;
    float* Wt     = ws + OFS_WT;
    int* cnt      = (int*)(ws + OFS_CNT);
    int* partial  = (int*)(ws + OFS_PART);
    int* bsum     = (int*)(ws + OFS_BSUM);
    int* offs     = (int*)(ws + OFS_OFFS);
    int* cursor   = (int*)(ws + OFS_CURS);
    int* perm     = (int*)(ws + OFS_PERM);
    int* psrc     = (int*)(ws + OFS_PSRC);

    hipMemsetAsync(cnt, 0, 50000 * sizeof(int), stream);
    hipMemsetAsync(cursor, 0, 50000 * sizeof(int), stream);

    relw_kernel<<<(20000 + 255) / 256, 256, 0, stream>>>(wcomp, ratt, relw);
    wt_kernel<<<(40000 + 255) / 256, 256, 0, stream>>>(Wkw, Wqw, Wvw, Wsw, Wt);
    proj_kernel<<<dim3((N_NODES + 63) / 64, 4), 256, 0, stream>>>(
        X, Wt, Wkb, Wqb, Wvb, Wsb, k, q, v, out);

    hist_kernel<<<(N_EDGES + 255) / 256, 256, 0, stream>>>(dst, cnt);
    scanA_kernel<<<SCAN_NB, 1024, 0, stream>>>(cnt, partial, bsum);
    scanB_kernel<<<1, 1024, 0, stream>>>(partial, bsum, offs);
    scatter_kernel<<<(N_EDGES + 255) / 256, 256, 0, stream>>>(src, dst, offs, cursor, perm, psrc);

    attp_kernel<<<(N_EDGES + 7) / 8, 256, 0, stream>>>(
        k, q, relw, perm, src, dst, ety, attp);
    agg_kernel<<<AGG_NB, 256, 0, stream>>>(offs, psrc, attp, v, alpha, out, bnpart);
    bnfin_kernel<<<25, 256, 0, stream>>>(bnpart, gamma, beta, bnsc, bnsh);
    apply_kernel<<<2048, 256, 0, stream>>>(out, bnsc, bnsh);
    rout_kernel<<<(20000 + 255) / 256, 256, 0, stream>>>(rfeat, Wrw, Wrb, out);
}